// Round 1
// baseline (986.098 us; speedup 1.0000x reference)
//
#include <hip/hip_runtime.h>

typedef __attribute__((ext_vector_type(8))) __bf16 bf16x8;
typedef __attribute__((ext_vector_type(4))) float f32x4;

#define DEV __device__ __forceinline__

DEV unsigned short f2bf(float f) {
  unsigned u = __float_as_uint(f);
  u = (u + 0x7fffu + ((u >> 16) & 1u)) >> 16;   // round-to-nearest-even
  return (unsigned short)u;
}
DEV float bf2f(unsigned short s) { return __uint_as_float(((unsigned)s) << 16); }
DEV float sigm(float x) { return 1.f / (1.f + expf(-x)); }

DEV uint4 pack8(f32x4 a, f32x4 b) {
  uint4 o;
  o.x = (unsigned)f2bf(a[0]) | ((unsigned)f2bf(a[1]) << 16);
  o.y = (unsigned)f2bf(a[2]) | ((unsigned)f2bf(a[3]) << 16);
  o.z = (unsigned)f2bf(b[0]) | ((unsigned)f2bf(b[1]) << 16);
  o.w = (unsigned)f2bf(b[2]) | ((unsigned)f2bf(b[3]) << 16);
  return o;
}

#define GL16(SRC, LDSB)                                                                    \
  __builtin_amdgcn_global_load_lds(                                                       \
      (const __attribute__((address_space(1))) unsigned int*)(SRC),                       \
      (__attribute__((address_space(3))) unsigned int*)(LDSB), 16, 0, 0)

// ---------------------------------------------------------------------------
// GEMM: C[M x N] = A[M x K] * B^T  (B stored [N x K] row-major, bf16 in/out-opt)
// 128x128 tile, BK=64, 4 waves, mfma 16x16x32 bf16, gload_lds + XOR swizzle.
// M % 128 == 0 required; N arbitrary (col-guarded); K % 64 == 0.
// ---------------------------------------------------------------------------
template<bool BIAS, bool OUTBF16>
__global__ __launch_bounds__(256)
void gemm_bt(const unsigned short* __restrict__ A, const unsigned short* __restrict__ Bm,
             const float* __restrict__ bias, void* __restrict__ Cv,
             int M, int N, int K)
{
  __shared__ unsigned short sm[16384];          // 32 KB: As[128][64], Bs[128][64]
  unsigned short* As = sm;
  unsigned short* Bs = sm + 8192;

  const int tid  = threadIdx.x;
  const int lane = tid & 63;
  const int wv   = tid >> 6;
  const int wr   = (wv >> 1) << 6;              // wave row offset (0/64)
  const int wc   = (wv & 1) << 6;               // wave col offset (0/64)
  const long mTile = (long)blockIdx.y << 7;
  const long nTile = (long)blockIdx.x << 7;

  const f32x4 z4 = {0.f, 0.f, 0.f, 0.f};
  f32x4 acc[4][4];
  #pragma unroll
  for (int i = 0; i < 4; ++i)
    #pragma unroll
    for (int j = 0; j < 4; ++j) acc[i][j] = z4;

  // staging geometry: 16 chunks of 1 KB per 16 KB tile; wave wv owns chunks wv*4+i.
  // dest is linear (gload_lds requirement); source address pre-applies the
  // involution kb ^= (row&7)<<4 so swizzled reads below see logical data.
  const int crow = lane >> 3;                   // row within chunk (0..7)
  const int ckb  = (lane & 7) << 4;             // linear kbyte of this lane's 16B

  for (int k0 = 0; k0 < K; k0 += 64) {
    #pragma unroll
    for (int i = 0; i < 4; ++i) {
      const int c   = (wv << 2) + i;            // chunk 0..15
      const int row = (c << 3) + crow;          // tile row 0..127
      const int kb  = ckb ^ ((row & 7) << 4);   // swizzled source kbyte
      const unsigned short* sA = A + (mTile + row) * K + k0 + (kb >> 1);
      GL16(sA, (char*)As + (c << 10));
      int bn = (int)nTile + row; bn = bn < N ? bn : (N - 1);   // clamp OOB cols
      const unsigned short* sB = Bm + (long)bn * K + k0 + (kb >> 1);
      GL16(sB, (char*)Bs + (c << 10));
    }
    __syncthreads();
    #pragma unroll
    for (int kk = 0; kk < 64; kk += 32) {
      const int kbl = (kk + ((lane >> 4) << 3)) << 1;   // logical kbyte of fragment
      bf16x8 af[4], bfv[4];
      #pragma unroll
      for (int mi = 0; mi < 4; ++mi) {
        const int r = wr + (mi << 4) + (lane & 15);
        af[mi] = *(const bf16x8*)((const char*)As + (r << 7) + (kbl ^ ((r & 7) << 4)));
      }
      #pragma unroll
      for (int ni = 0; ni < 4; ++ni) {
        const int r = wc + (ni << 4) + (lane & 15);
        bfv[ni] = *(const bf16x8*)((const char*)Bs + (r << 7) + (kbl ^ ((r & 7) << 4)));
      }
      #pragma unroll
      for (int mi = 0; mi < 4; ++mi)
        #pragma unroll
        for (int ni = 0; ni < 4; ++ni)
          acc[mi][ni] = __builtin_amdgcn_mfma_f32_16x16x32_bf16(af[mi], bfv[ni], acc[mi][ni], 0, 0, 0);
    }
    __syncthreads();
  }

  // epilogue: C/D layout col=lane&15, row=(lane>>4)*4+j (m89-verified)
  #pragma unroll
  for (int ni = 0; ni < 4; ++ni) {
    const long col = nTile + wc + (ni << 4) + (lane & 15);
    if (col < N) {
      float bv = 0.f;
      if constexpr (BIAS) bv = bias[col];
      #pragma unroll
      for (int mi = 0; mi < 4; ++mi) {
        const long row = mTile + wr + (mi << 4) + ((lane >> 4) << 2);
        #pragma unroll
        for (int j = 0; j < 4; ++j) {
          const float v = acc[mi][ni][j] + bv;
          if constexpr (OUTBF16) ((unsigned short*)Cv)[(row + j) * N + col] = f2bf(v);
          else                   ((float*)Cv)[(row + j) * N + col] = v;
        }
      }
    }
  }
}

// ---------------------------------------------------------------------------
// Elementwise / graph kernels
// ---------------------------------------------------------------------------
__global__ void k_cvt8(const float* __restrict__ in, unsigned short* __restrict__ out, long n8)
{
  const long i = (long)blockIdx.x * 256 + threadIdx.x;
  if (i >= n8) return;
  const f32x4 a = *(const f32x4*)(in + i * 8);
  const f32x4 b = *(const f32x4*)(in + i * 8 + 4);
  *(uint4*)(out + i * 8) = pack8(a, b);
}

__global__ void k_tr(const float* __restrict__ g, unsigned short* __restrict__ o)
{
  const int mat = blockIdx.x >> 8;
  const int n   = blockIdx.x & 255;
  const int k   = threadIdx.x;
  o[mat * 65536 + n * 256 + k] = f2bf(g[mat * 65536 + k * 256 + n]);
}

__global__ void k_b12(const float* __restrict__ b1, const float* __restrict__ b2,
                      float* __restrict__ o)
{
  o[threadIdx.x] = b1[threadIdx.x] + b2[threadIdx.x];
}

__global__ void k_gather(const int* __restrict__ x, const float* __restrict__ emb,
                         unsigned short* __restrict__ h)
{
  const long i = (long)blockIdx.x * 256 + threadIdx.x;   // one per 8 dims
  const long node = i >> 5;
  const int  d0 = ((int)i & 31) << 3;
  const long row = (long)x[node] - 1;                    // 1-based ids
  const float* p = emb + row * 256 + d0;
  const f32x4 a = *(const f32x4*)p;
  const f32x4 b = *(const f32x4*)(p + 4);
  *(uint4*)(h + node * 256 + d0) = pack8(a, b);
}

// per-graph scatter-add: block g handles its 20 nodes / 40 edges; thread owns dim d
__global__ void k_scatter(const unsigned short* __restrict__ m, const int* __restrict__ ei,
                          unsigned short* __restrict__ agg, int E)
{
  __shared__ float aggs[20 * 256];
  __shared__ int es[40], ed[40];
  const int g = blockIdx.x;
  const int d = threadIdx.x;
  if (d < 40) es[d] = ei[g * 40 + d];
  if (d >= 128 && d < 168) ed[d - 128] = ei[E + g * 40 + (d - 128)];
  #pragma unroll
  for (int i = 0; i < 20; ++i) aggs[i * 256 + d] = 0.f;
  __syncthreads();
  for (int e = 0; e < 40; ++e) {
    const float mv = bf2f(m[(long)es[e] * 256 + d]);
    const int loc = ed[e] - g * 20;
    aggs[loc * 256 + d] += mv;     // thread-private column: no races
  }
  const long base = (long)g * (20 * 256);
  #pragma unroll
  for (int i = 0; i < 20; ++i)
    agg[base + i * 256 + d] = f2bf(aggs[i * 256 + d]);
}

__global__ void k_gru(const unsigned short* __restrict__ gi, const unsigned short* __restrict__ gh,
                      unsigned short* __restrict__ h)
{
  const long i = (long)blockIdx.x * 256 + threadIdx.x;   // one per 8 dims
  const long node = i >> 5;
  const int  d0 = ((int)i & 31) << 3;
  const long gb = node * 768 + d0;
  const uint4 vir = *(const uint4*)(gi + gb);
  const uint4 viz = *(const uint4*)(gi + gb + 256);
  const uint4 vin = *(const uint4*)(gi + gb + 512);
  const uint4 vhr = *(const uint4*)(gh + gb);
  const uint4 vhz = *(const uint4*)(gh + gb + 256);
  const uint4 vhn = *(const uint4*)(gh + gb + 512);
  const long hb = node * 256 + d0;
  const uint4 vh = *(const uint4*)(h + hb);
  uint4 outv;
  unsigned* po = (unsigned*)&outv;
  #pragma unroll
  for (int j = 0; j < 4; ++j) {
    unsigned res = 0;
    #pragma unroll
    for (int t = 0; t < 2; ++t) {
      const int sh = t * 16;
      const float ir  = bf2f((unsigned short)(((const unsigned*)&vir)[j] >> sh));
      const float iz  = bf2f((unsigned short)(((const unsigned*)&viz)[j] >> sh));
      const float inn = bf2f((unsigned short)(((const unsigned*)&vin)[j] >> sh));
      const float hr  = bf2f((unsigned short)(((const unsigned*)&vhr)[j] >> sh));
      const float hz  = bf2f((unsigned short)(((const unsigned*)&vhz)[j] >> sh));
      const float hn  = bf2f((unsigned short)(((const unsigned*)&vhn)[j] >> sh));
      const float hv  = bf2f((unsigned short)(((const unsigned*)&vh )[j] >> sh));
      const float r  = sigm(ir + hr);
      const float zz = sigm(iz + hz);
      const float nn = tanhf(inn + r * hn);
      const float o  = (1.f - zz) * nn + zz * hv;
      res |= ((unsigned)f2bf(o)) << sh;
    }
    po[j] = res;
  }
  *(uint4*)(h + hb) = outv;
}

__global__ void k_lastidx(const int* __restrict__ batch, int* __restrict__ last, int n, int ng)
{
  const int g = blockIdx.x * blockDim.x + threadIdx.x;
  if (g >= ng) return;
  int lo = 0, hi = n;                     // first idx with batch[idx] > g
  while (lo < hi) { const int mid = (lo + hi) >> 1; if (batch[mid] > g) hi = mid; else lo = mid + 1; }
  last[g] = lo - 1;
}

__global__ void k_vn(const unsigned short* __restrict__ h, const int* __restrict__ last,
                     unsigned short* __restrict__ vn, unsigned short* __restrict__ cat)
{
  const long i = (long)blockIdx.x * 256 + threadIdx.x;
  const long g = i >> 5;
  const int  d0 = ((int)i & 31) << 3;
  const uint4 v = *(const uint4*)(h + (long)last[g] * 256 + d0);
  *(uint4*)(vn + g * 256 + d0) = v;
  *(uint4*)(cat + g * 512 + d0) = v;
}

__global__ void k_alpha(const float* __restrict__ vw1, const float* __restrict__ hw2,
                        const int* __restrict__ batch, const float* __restrict__ qw,
                        const float* __restrict__ qb, float* __restrict__ alpha)
{
  const int wv = threadIdx.x >> 6;
  const int lane = threadIdx.x & 63;
  const long n = (long)blockIdx.x * 4 + wv;
  const int d = lane << 2;
  const f32x4 a  = *(const f32x4*)(hw2 + n * 256 + d);
  const f32x4 vb = *(const f32x4*)(vw1 + (long)batch[n] * 256 + d);
  const f32x4 qv = *(const f32x4*)(qw + d);
  float s = 0.f;
  #pragma unroll
  for (int j = 0; j < 4; ++j) s += sigm(a[j] + vb[j]) * qv[j];
  #pragma unroll
  for (int off = 32; off > 0; off >>= 1) s += __shfl_xor(s, off, 64);
  if (lane == 0) alpha[n] = s + qb[0];
}

__global__ void k_sg(const float* __restrict__ alpha, const unsigned short* __restrict__ h,
                     unsigned short* __restrict__ cat)
{
  __shared__ float al[20];
  const int g = blockIdx.x, d = threadIdx.x;
  if (d < 20) al[d] = alpha[g * 20 + d];
  __syncthreads();
  float s = 0.f;
  const unsigned short* hp = h + (long)g * 20 * 256 + d;
  #pragma unroll
  for (int i = 0; i < 20; ++i) s += al[i] * bf2f(hp[i * 256]);
  cat[(long)g * 512 + 256 + d] = f2bf(s);
}

// ---------------------------------------------------------------------------
extern "C" void kernel_launch(void* const* d_in, const int* in_sizes, int n_in,
                              void* d_out, int out_size, void* d_ws, size_t ws_size,
                              hipStream_t stream)
{
  const int*   x     = (const int*)  d_in[0];
  const int*   ei    = (const int*)  d_in[1];
  const int*   batch = (const int*)  d_in[2];
  const float* emb   = (const float*)d_in[3];
  const float* gw    = (const float*)d_in[4];
  const float* wih   = (const float*)d_in[5];
  const float* whh   = (const float*)d_in[6];
  const float* bih   = (const float*)d_in[7];
  const float* bhh   = (const float*)d_in[8];
  const float* W1    = (const float*)d_in[9];
  const float* b1    = (const float*)d_in[10];
  const float* W2    = (const float*)d_in[11];
  const float* b2    = (const float*)d_in[12];
  const float* qw    = (const float*)d_in[13];
  const float* qb    = (const float*)d_in[14];
  const float* W3    = (const float*)d_in[15];
  const float* b3    = (const float*)d_in[16];

  const int Nn = in_sizes[0];           // 81920 nodes
  const int E  = in_sizes[1] / 2;       // 163840 edges
  const int V  = in_sizes[3] / 256;     // 50000 vocab
  const int B  = out_size / V;          // 4096 graphs

  char* w = (char*)d_ws;
  auto take = [&](size_t bytes) { char* r = w; w += (bytes + 1023) & ~(size_t)1023; return r; };
  unsigned short* h_   = (unsigned short*)take((size_t)Nn * 256 * 2);
  unsigned short* m_   = (unsigned short*)take((size_t)Nn * 256 * 2);
  unsigned short* agg_ = (unsigned short*)take((size_t)Nn * 256 * 2);
  unsigned short* gi_  = (unsigned short*)take((size_t)Nn * 768 * 2);
  unsigned short* gh_  = (unsigned short*)take((size_t)Nn * 768 * 2);
  unsigned short* embb = (unsigned short*)take((size_t)V * 256 * 2);
  unsigned short* gtw  = (unsigned short*)take((size_t)2 * 65536 * 2);
  unsigned short* wihb = (unsigned short*)take((size_t)768 * 256 * 2);
  unsigned short* whhb = (unsigned short*)take((size_t)768 * 256 * 2);
  unsigned short* w1b  = (unsigned short*)take((size_t)65536 * 2);
  unsigned short* w2b  = (unsigned short*)take((size_t)65536 * 2);
  unsigned short* w3b  = (unsigned short*)take((size_t)131072 * 2);
  unsigned short* vnb  = (unsigned short*)take((size_t)B * 256 * 2);
  unsigned short* catb = (unsigned short*)take((size_t)B * 512 * 2);
  unsigned short* shb  = (unsigned short*)take((size_t)B * 256 * 2);
  float*          b12  = (float*)take(256 * 4);
  int*            last = (int*)take((size_t)B * 4);
  float*          alph = (float*)take((size_t)Nn * 4);
  // readout f32 buffers alias the (dead-after-layers) gi/gh regions
  float* hw2 = (float*)gi_;             // Nn*256*4 = 84 MB <= 126 MB
  float* vw1 = (float*)gh_;             // B*256*4 = 4.2 MB

  // --- prep: bf16 conversions (+ gated_w transpose), fused biases ---
  k_cvt8<<<dim3(((long)V * 256 / 8 + 255) / 256), 256, 0, stream>>>(emb, embb, (long)V * 256 / 8);
  k_tr  <<<dim3(512), 256, 0, stream>>>(gw, gtw);
  k_cvt8<<<dim3(96),  256, 0, stream>>>(wih, wihb, 768 * 256 / 8);
  k_cvt8<<<dim3(96),  256, 0, stream>>>(whh, whhb, 768 * 256 / 8);
  k_cvt8<<<dim3(32),  256, 0, stream>>>(W1, w1b, 65536 / 8);
  k_cvt8<<<dim3(32),  256, 0, stream>>>(W2, w2b, 65536 / 8);
  k_cvt8<<<dim3(64),  256, 0, stream>>>(W3, w3b, 131072 / 8);
  k_b12 <<<dim3(1),   256, 0, stream>>>(b1, b2, b12);
  k_gather<<<dim3(Nn * 32 / 256), 256, 0, stream>>>(x, emb, h_);

  // --- 2x GatedGraphConv + GRUCell ---
  for (int L = 0; L < 2; ++L) {
    gemm_bt<false, true><<<dim3(2, Nn / 128), 256, 0, stream>>>(h_, gtw + (size_t)L * 65536, nullptr, m_, Nn, 256, 256);
    k_scatter<<<dim3(B), 256, 0, stream>>>(m_, ei, agg_, E);
    gemm_bt<true, true><<<dim3(6, Nn / 128), 256, 0, stream>>>(agg_, wihb, bih, gi_, Nn, 768, 256);
    gemm_bt<true, true><<<dim3(6, Nn / 128), 256, 0, stream>>>(h_, whhb, bhh, gh_, Nn, 768, 256);
    k_gru<<<dim3(Nn * 32 / 256), 256, 0, stream>>>(gi_, gh_, h_);
  }

  // --- attention readout ---
  k_lastidx<<<dim3((B + 255) / 256), 256, 0, stream>>>(batch, last, Nn, B);
  k_vn<<<dim3(B * 32 / 256), 256, 0, stream>>>(h_, last, vnb, catb);
  gemm_bt<true, false><<<dim3(2, B / 128), 256, 0, stream>>>(vnb, w1b, b12, vw1, B, 256, 256);
  gemm_bt<false, false><<<dim3(2, Nn / 128), 256, 0, stream>>>(h_, w2b, nullptr, hw2, Nn, 256, 256);
  k_alpha<<<dim3(Nn / 4), 256, 0, stream>>>(vw1, hw2, batch, qw, qb, alph);
  k_sg<<<dim3(B), 256, 0, stream>>>(alph, h_, catb);
  gemm_bt<true, true><<<dim3(2, B / 128), 256, 0, stream>>>(catb, w3b, b3, shb, B, 256, 512);

  // --- scores = s_h @ emb^T -> d_out (f32) ---
  gemm_bt<false, false><<<dim3((V + 127) / 128, B / 128), 256, 0, stream>>>(shb, embb, nullptr, (float*)d_out, B, V, 256);

  (void)n_in; (void)ws_size; (void)batch;
}